// Round 1
// baseline (725.254 us; speedup 1.0000x reference)
//
#include <hip/hip_runtime.h>

typedef __attribute__((ext_vector_type(8))) short short8;
typedef __attribute__((ext_vector_type(4))) float f32x4;

#define T_SIZE (1u << 22)
#define HMASK 0x3FFFFFu
#define P2H 2654435761u
#define P3H 805459861u
#define FLD 104   // feat LDS row stride (ushorts), 96 used + pad (16B-aligned rows)
#define HLD 264   // hidden LDS row stride (ushorts), 256 used + pad

__constant__ float c_RES[24] = {
    16.f, 24.f, 36.f, 54.f, 81.f, 121.f, 182.f, 273.f, 410.f, 615.f,
    922.f, 1383.f, 2075.f, 3113.f, 4670.f, 7006.f, 10509.f, 15764.f,
    23646.f, 35469.f, 53204.f, 79806.f, 119709.f, 179563.f};

static __device__ __forceinline__ ushort f2bf(float f) {
    union { float f; unsigned u; } v; v.f = f;
    unsigned r = v.u + 0x7FFFu + ((v.u >> 16) & 1u);
    return (ushort)(r >> 16);
}
static __device__ __forceinline__ float bf2f(ushort u) {
    union { unsigned u; float f; } v; v.u = ((unsigned)u) << 16; return v.f;
}

// Transpose + bf16-convert W1 (96x256) and W2 (256x256) into ws: Wt[n][k].
__global__ void prep_weights(const float* __restrict__ W1, const float* __restrict__ W2,
                             ushort* __restrict__ Wt1, ushort* __restrict__ Wt2) {
    int id = blockIdx.x * 256 + threadIdx.x;
    if (id < 96 * 256) {
        int n = id / 96, k = id - n * 96;
        Wt1[id] = f2bf(W1[k * 256 + n]);
    }
    int id2 = id - 96 * 256;
    if (id2 >= 0 && id2 < 256 * 256) {
        int n = id2 >> 8, k = id2 & 255;
        Wt2[id2] = f2bf(W2[k * 256 + n]);
    }
}

__global__ __launch_bounds__(256) void fused_ngp(
    const float4* __restrict__ coords,
    const float* __restrict__ stab,
    const float* __restrict__ ttab,
    const ushort* __restrict__ Wt1,
    const float* __restrict__ b1,
    const ushort* __restrict__ Wt2,
    const float* __restrict__ b2,
    const float* __restrict__ W3,
    const float* __restrict__ b3,
    float* __restrict__ out) {
    __shared__ ushort feat_lds[64 * FLD];  // 13312 B
    __shared__ ushort h_lds[64 * HLD];     // 33792 B (h1 then h2)
    __shared__ float w3_lds[256 * 3 + 4];  // 3088 B

    const int tid = threadIdx.x;

    // stage W3 (256x3) + b3 into LDS
    for (int i = tid; i < 768; i += 256) w3_lds[i] = W3[i];
    if (tid < 3) w3_lds[768 + tid] = b3[tid];

    // ---------------- encode: 64 points x 24 levels; 4 threads/point ----------
    const int p = tid & 63;
    const int g = tid >> 6;  // level group 0..3 -> levels g*6 .. g*6+5
    const float4 c = coords[blockIdx.x * 64 + p];

    #pragma unroll
    for (int dl = 0; dl < 6; ++dl) {
        const int l = g * 6 + dl;
        const float R = c_RES[l];

        // spatial (x,y,z)
        float sx = c.x * R, sy = c.y * R, sz = c.z * R;
        float bx = floorf(sx), by = floorf(sy), bz = floorf(sz);
        float fx = sx - bx, fy = sy - by, fz = sz - bz;
        unsigned ux = (unsigned)(int)bx, uy = (unsigned)(int)by, uz = (unsigned)(int)bz;
        unsigned hx0 = ux, hx1 = ux + 1u;
        unsigned hy0 = uy * P2H, hy1 = hy0 + P2H;
        unsigned hz0 = uz * P3H, hz1 = hz0 + P3H;

        const float2* tl = (const float2*)stab + (size_t)l * T_SIZE;
        unsigned h[8];
        h[0] = (hx0 ^ hy0 ^ hz0) & HMASK; h[1] = (hx0 ^ hy0 ^ hz1) & HMASK;
        h[2] = (hx0 ^ hy1 ^ hz0) & HMASK; h[3] = (hx0 ^ hy1 ^ hz1) & HMASK;
        h[4] = (hx1 ^ hy0 ^ hz0) & HMASK; h[5] = (hx1 ^ hy0 ^ hz1) & HMASK;
        h[6] = (hx1 ^ hy1 ^ hz0) & HMASK; h[7] = (hx1 ^ hy1 ^ hz1) & HMASK;
        float2 e[8];
        #pragma unroll
        for (int q = 0; q < 8; ++q) e[q] = tl[h[q]];

        float wx0 = 1.f - fx, wy0 = 1.f - fy, wz0 = 1.f - fz;
        float w[8] = {wx0 * wy0 * wz0, wx0 * wy0 * fz, wx0 * fy * wz0, wx0 * fy * fz,
                      fx * wy0 * wz0,  fx * wy0 * fz,  fx * fy * wz0,  fx * fy * fz};
        float f0 = 0.f, f1 = 0.f;
        #pragma unroll
        for (int q = 0; q < 8; ++q) { f0 = fmaf(w[q], e[q].x, f0); f1 = fmaf(w[q], e[q].y, f1); }
        feat_lds[p * FLD + 2 * l]     = f2bf(f0);
        feat_lds[p * FLD + 2 * l + 1] = f2bf(f1);

        // temporal (t)
        float st = c.w * R;
        float btf = floorf(st);
        float ft = st - btf;
        unsigned ut = (unsigned)(int)btf;
        unsigned th0 = (ut * P2H) & HMASK;
        unsigned th1 = ((ut + 1u) * P2H) & HMASK;
        const float2* ttl = (const float2*)ttab + (size_t)l * T_SIZE;
        float2 e0 = ttl[th0], e1 = ttl[th1];
        feat_lds[p * FLD + 48 + 2 * l]     = f2bf((1.f - ft) * e0.x + ft * e1.x);
        feat_lds[p * FLD + 48 + 2 * l + 1] = f2bf((1.f - ft) * e0.y + ft * e1.y);
    }
    __syncthreads();

    // ---------------- layer 1: (64x96) @ (96x256), wave wv owns N cols [wv*64, wv*64+64)
    const int lane = tid & 63;
    const int wv = tid >> 6;
    const int lr = lane & 15;
    const int lk = (lane >> 4) * 8;
    const int nb = wv * 64;
    const int rbase = (lane >> 4) * 4;

    f32x4 acc[4][4] = {};
    #pragma unroll
    for (int ks = 0; ks < 3; ++ks) {
        short8 a[4], b[4];
        #pragma unroll
        for (int mi = 0; mi < 4; ++mi)
            a[mi] = *(const short8*)&feat_lds[(mi * 16 + lr) * FLD + ks * 32 + lk];
        #pragma unroll
        for (int ni = 0; ni < 4; ++ni)
            b[ni] = *(const short8*)&Wt1[(size_t)(nb + ni * 16 + lr) * 96 + ks * 32 + lk];
        #pragma unroll
        for (int mi = 0; mi < 4; ++mi)
            #pragma unroll
            for (int ni = 0; ni < 4; ++ni)
                acc[mi][ni] = __builtin_amdgcn_mfma_f32_16x16x32_bf16(a[mi], b[ni], acc[mi][ni], 0, 0, 0);
    }
    {
        float bn[4];
        #pragma unroll
        for (int ni = 0; ni < 4; ++ni) bn[ni] = b1[nb + ni * 16 + lr];
        #pragma unroll
        for (int mi = 0; mi < 4; ++mi)
            #pragma unroll
            for (int ni = 0; ni < 4; ++ni)
                #pragma unroll
                for (int r = 0; r < 4; ++r)
                    h_lds[(mi * 16 + rbase + r) * HLD + nb + ni * 16 + lr] =
                        f2bf(fmaxf(acc[mi][ni][r] + bn[ni], 0.f));
    }
    __syncthreads();

    // ---------------- layer 2: (64x256) @ (256x256)
    f32x4 acc2[4][4] = {};
    #pragma unroll
    for (int ks = 0; ks < 8; ++ks) {
        short8 a[4], b[4];
        #pragma unroll
        for (int mi = 0; mi < 4; ++mi)
            a[mi] = *(const short8*)&h_lds[(mi * 16 + lr) * HLD + ks * 32 + lk];
        #pragma unroll
        for (int ni = 0; ni < 4; ++ni)
            b[ni] = *(const short8*)&Wt2[(size_t)(nb + ni * 16 + lr) * 256 + ks * 32 + lk];
        #pragma unroll
        for (int mi = 0; mi < 4; ++mi)
            #pragma unroll
            for (int ni = 0; ni < 4; ++ni)
                acc2[mi][ni] = __builtin_amdgcn_mfma_f32_16x16x32_bf16(a[mi], b[ni], acc2[mi][ni], 0, 0, 0);
    }
    __syncthreads();  // all h1 reads done before overwrite
    {
        float bn2[4];
        #pragma unroll
        for (int ni = 0; ni < 4; ++ni) bn2[ni] = b2[nb + ni * 16 + lr];
        #pragma unroll
        for (int mi = 0; mi < 4; ++mi)
            #pragma unroll
            for (int ni = 0; ni < 4; ++ni)
                #pragma unroll
                for (int r = 0; r < 4; ++r)
                    h_lds[(mi * 16 + rbase + r) * HLD + nb + ni * 16 + lr] =
                        f2bf(fmaxf(acc2[mi][ni][r] + bn2[ni], 0.f));
    }
    __syncthreads();

    // ---------------- layer 3: (64x256) @ (256x3) + sigmoid, one thread per (point, channel)
    if (tid < 192) {
        const int pp = tid / 3;
        const int cc = tid - 3 * pp;
        float s = w3_lds[768 + cc];
        #pragma unroll 8
        for (int k = 0; k < 256; ++k)
            s = fmaf(bf2f(h_lds[pp * HLD + k]), w3_lds[k * 3 + cc], s);
        out[(size_t)(blockIdx.x * 64 + pp) * 3 + cc] = 1.f / (1.f + expf(-s));
    }
}

extern "C" void kernel_launch(void* const* d_in, const int* in_sizes, int n_in,
                              void* d_out, int out_size, void* d_ws, size_t ws_size,
                              hipStream_t stream) {
    const float* coords = (const float*)d_in[0];
    const float* stab   = (const float*)d_in[1];
    const float* ttab   = (const float*)d_in[2];
    const float* W1     = (const float*)d_in[3];
    const float* b1     = (const float*)d_in[4];
    const float* W2     = (const float*)d_in[5];
    const float* b2     = (const float*)d_in[6];
    const float* W3     = (const float*)d_in[7];
    const float* b3     = (const float*)d_in[8];

    ushort* Wt1 = (ushort*)d_ws;            // 96*256 bf16
    ushort* Wt2 = Wt1 + 96 * 256;           // 256*256 bf16

    prep_weights<<<352, 256, 0, stream>>>(W1, W2, Wt1, Wt2);

    const int B = in_sizes[0] / 4;          // 262144
    fused_ngp<<<B / 64, 256, 0, stream>>>((const float4*)coords, stab, ttab,
                                          Wt1, b1, Wt2, b2, W3, b3, (float*)d_out);
}